// Round 3
// baseline (678.979 us; speedup 1.0000x reference)
//
#include <hip/hip_runtime.h>

// Partial-CRF NLL via MFMA. 64 blocks x 512 threads; block = 8 batches x
// {all-paths, gold} = 16 chains. Per step t: new^T = E^T (regs) * P^T (LDS),
// one mfma_f32_16x16x32_bf16 K-chain per wave-owned 16-tag tile.
// P stored raw (unnormalized) in bf16; scale 1/P_old[chain][tag1] applied in
// the NEXT step's epilogue (deferred rescale); logZ += log(P_old[1]) on
// active steps, tracked by wave 0 lanes 0..15. Masked chains: P_new = P_old
// (per-row select, old values re-read from prev buffer). Double-buffered P,
// ONE barrier per step. 2-deep global prefetch of emit/um/mask.

typedef short bf16x8 __attribute__((ext_vector_type(8)));
typedef short s16x4  __attribute__((ext_vector_type(4)));
typedef float f32x4  __attribute__((ext_vector_type(4)));

constexpr int B = 512, T = 512, L = 102;
constexpr int START = 100, STOP = 101;
constexpr int KP = 136;   // P row pad: 272 B -> bank stride 4 (2-way max)
constexpr int EP = 104;   // staged-E row pad

__device__ __forceinline__ float bf2f(short s) {
  return __uint_as_float(((unsigned int)(unsigned short)s) << 16);
}
__device__ __forceinline__ short f2bf(float x) {  // RNE
  unsigned int u = __float_as_uint(x);
  u += 0x7fffu + ((u >> 16) & 1u);
  return (short)(u >> 16);
}

__global__ __launch_bounds__(512)
void crf_fwd(const float* __restrict__ emit,
             const float* __restrict__ trans,
             const unsigned char* __restrict__ mask_b,
             const unsigned char* __restrict__ um_b,
             float* __restrict__ partials)
{
  const int tid  = threadIdx.x;
  const int wid  = tid >> 6;
  const int lane = tid & 63;
  const int m    = lane & 15;            // chain 0..15
  const int hi   = lane >> 4;            // 0..3
  const int tagbase = 16 * wid + 4 * hi; // 0..124 (D-frag tag base)
  const int batch = blockIdx.x * 8 + (m >> 1);
  const int goldc = m & 1;

  // bool layout: um[0,0,1] always True -> byte1==1 iff uint8, else LE int32
  const int ushift = (um_b[1] != 0) ? 0 : 2;

  __shared__ __align__(16) short Pl[2][16][KP];
  __shared__ __align__(16) short El[L][EP];
  __shared__ float wpart[8][16];

  const float* __restrict__ ebase = emit + (size_t)batch * T * L;
  const unsigned char* __restrict__ ub =
      um_b + (((size_t)batch * T * L) << ushift);
  const unsigned char* __restrict__ mb =
      mask_b + (((size_t)batch * T) << ushift);

  // ---- stage E = exp(trans) as bf16 in LDS (coalesced, one-time) ----
  for (int i = tid; i < L * L; i += 512) {
    int k = i / L, n = i - k * L;
    El[k][n] = f2bf(__expf(trans[i]));
  }
  { // zero both P buffers (incl. pads)
    short* pz = &Pl[0][0][0];
    for (int i = tid; i < 2 * 16 * KP; i += 512) pz[i] = 0;
  }
  __syncthreads();

  // ---- A-frags: E^T rows = wave's tags. lane: tag=16w+(l&15), k=8*hi+i ----
  const int mytag = 16 * wid + m;
  bf16x8 ef[4];
#pragma unroll
  for (int kk = 0; kk < 4; ++kk) {
    bf16x8 v;
#pragma unroll
    for (int i = 0; i < 8; ++i) {
      const int k = 32 * kk + 8 * hi + i;
      v[i] = (mytag < L && k < L) ? El[k][mytag] : (short)0;
    }
    ef[kk] = v;
  }

  // ---- t = 0: P0 = exp(e0 + trans[START][tag]) (gold: um-masked) ----
  {
    const int ta = min(tagbase, 100), tb = min(tagbase + 2, 100);
    const float2 ea  = *(const float2*)(ebase + ta);
    const float2 eb2 = *(const float2*)(ebase + tb);
    const float ev[4] = {ea.x, ea.y, eb2.x, eb2.y};
    s16x4 o;
#pragma unroll
    for (int r = 0; r < 4; ++r) {
      const int tag = tagbase + r;
      float val = 0.f;
      if (tag < L) {
        float x = __expf(ev[r] + trans[START * L + tag]);
        const unsigned char u = ub[(size_t)tag << ushift];
        if (goldc && !u) x = 0.f;
        val = x;
      }
      o[r] = f2bf(val);
    }
    *(s16x4*)(&Pl[0][m][tagbase]) = o;
  }

  // ---- prefetch state (static slots A/B; rule #20: no runtime indexing) ---
  float2 pA0, pA1, pB0, pB1;
  unsigned char uA0, uA1, uA2, uA3, mA, uB0, uB1, uB2, uB3, mB;

  auto issue = [&](int t, float2& p0, float2& p1, unsigned char& u0,
                   unsigned char& u1, unsigned char& u2, unsigned char& u3,
                   unsigned char& mm) {
    const int tc = min(t, T - 1);
    const float* ep = ebase + tc * L;
    const int ta = min(tagbase, 100), tb = min(tagbase + 2, 100);
    p0 = *(const float2*)(ep + ta);
    p1 = *(const float2*)(ep + tb);
    const unsigned char* up = ub + (((size_t)tc * L) << ushift);
    u0 = up[(size_t)min(tagbase + 0, 101) << ushift];
    u1 = up[(size_t)min(tagbase + 1, 101) << ushift];
    u2 = up[(size_t)min(tagbase + 2, 101) << ushift];
    u3 = up[(size_t)min(tagbase + 3, 101) << ushift];
    mm = mb[(size_t)tc << ushift];
  };

  float logZl = 0.f;
  const f32x4 zf = {0.f, 0.f, 0.f, 0.f};

  auto step = [&](int t, const short (*src)[KP], short (*dst)[KP], float2 p0,
                  float2 p1, unsigned char u0, unsigned char u1,
                  unsigned char u2, unsigned char u3, unsigned char mm) {
    const short* Prow = &src[m][0];
    const bf16x8 b0 = *(const bf16x8*)(Prow + 0  + 8 * hi);
    const bf16x8 b1 = *(const bf16x8*)(Prow + 32 + 8 * hi);
    const bf16x8 b2 = *(const bf16x8*)(Prow + 64 + 8 * hi);
    const bf16x8 b3 = *(const bf16x8*)(Prow + 96 + 8 * hi);
    const short s1s = Prow[1];
    const s16x4 oldp = *(const s16x4*)(Prow + tagbase);
    const float s1f = bf2f(s1s);
    const float c = __builtin_amdgcn_rcpf(s1f);

    f32x4 a0 = __builtin_amdgcn_mfma_f32_16x16x32_bf16(ef[0], b0, zf, 0, 0, 0);
    f32x4 a1 = __builtin_amdgcn_mfma_f32_16x16x32_bf16(ef[1], b1, zf, 0, 0, 0);
    a0 = __builtin_amdgcn_mfma_f32_16x16x32_bf16(ef[2], b2, a0, 0, 0, 0);
    a1 = __builtin_amdgcn_mfma_f32_16x16x32_bf16(ef[3], b3, a1, 0, 0, 0);

    const int mcur = (t < T) ? (int)mm : 0;   // step 512 = harmless copy
    const float ex0 = __expf(p0.x), ex1 = __expf(p0.y);
    const float ex2 = __expf(p1.x), ex3 = __expf(p1.y);
    float v0 = (a0[0] + a1[0]) * c * ex0;
    float v1 = (a0[1] + a1[1]) * c * ex1;
    float v2 = (a0[2] + a1[2]) * c * ex2;
    float v3 = (a0[3] + a1[3]) * c * ex3;
    if (goldc && !u0) v0 = 0.f;
    if (goldc && !u1) v1 = 0.f;
    if (goldc && !u2) v2 = 0.f;
    if (goldc && !u3) v3 = 0.f;
    s16x4 o;
    o[0] = mcur ? f2bf(v0) : oldp[0];
    o[1] = mcur ? f2bf(v1) : oldp[1];
    o[2] = mcur ? f2bf(v2) : oldp[2];
    o[3] = mcur ? f2bf(v3) : oldp[3];
    *(s16x4*)(&dst[m][tagbase]) = o;

    if (wid == 0) {                       // logZ bookkeeping: lanes 0..15
      const float lg = __logf(s1f);
      if (lane < 16 && mcur) logZl += lg;
    }
    __syncthreads();
  };

  __syncthreads();                        // t0 writes + frag fills visible
  issue(1, pA0, pA1, uA0, uA1, uA2, uA3, mA);
  issue(2, pB0, pB1, uB0, uB1, uB2, uB3, mB);

  for (int t = 1; t <= 511; t += 2) {
    const float2 c0 = pA0, c1 = pA1;
    const unsigned char x0 = uA0, x1 = uA1, x2 = uA2, x3 = uA3, xm = mA;
    issue(t + 2, pA0, pA1, uA0, uA1, uA2, uA3, mA);   // in flight 2 steps
    step(t, Pl[0], Pl[1], c0, c1, x0, x1, x2, x3, xm);

    const float2 d0 = pB0, d1 = pB1;
    const unsigned char y0 = uB0, y1 = uB1, y2 = uB2, y3 = uB3, ym = mB;
    issue(t + 3, pB0, pB1, uB0, uB1, uB2, uB3, mB);
    step(t + 1, Pl[1], Pl[0], d0, d1, y0, y1, y2, y3, ym);
  }
  // 511 real steps + forced-copy step 512 -> final P is in Pl[0]

  // ---- final: score[m] = logZ[m] + log sum_n P[m][n]*exp(trans[n][STOP]) --
  float accf = 0.f;
  {
    const int q = tid >> 4;   // 0..31
#pragma unroll
    for (int j = 0; j < 4; ++j) {
      const int nn = q + 32 * j;
      if (nn < L) accf += bf2f(Pl[0][m][nn]) * __expf(trans[nn * L + STOP]);
    }
  }
  accf += __shfl_xor(accf, 16);
  accf += __shfl_xor(accf, 32);
  if (lane < 16) wpart[wid][lane] = accf;
  __syncthreads();
  if (wid == 0 && lane < 16) {
    float tot = 0.f;
#pragma unroll
    for (int w = 0; w < 8; ++w) tot += wpart[w][lane];
    float cs = logZl + __logf(tot);
    float sgn = (lane & 1) ? -cs : cs;    // odd chains = gold (negated)
    sgn += __shfl_xor(sgn, 1);
    sgn += __shfl_xor(sgn, 2);
    sgn += __shfl_xor(sgn, 4);
    sgn += __shfl_xor(sgn, 8);
    if (lane == 0) partials[blockIdx.x] = sgn;
  }
}

__global__ void reduce_partials(const float* __restrict__ part,
                                float* __restrict__ out) {
  float v = part[threadIdx.x];
#pragma unroll
  for (int s = 1; s < 64; s <<= 1) v += __shfl_xor(v, s);
  if (threadIdx.x == 0) out[0] = v;
}

extern "C" void kernel_launch(void* const* d_in, const int* in_sizes, int n_in,
                              void* d_out, int out_size, void* d_ws,
                              size_t ws_size, hipStream_t stream) {
  const float* emit = (const float*)d_in[0];
  const float* trn  = (const float*)d_in[1];
  const unsigned char* msk = (const unsigned char*)d_in[2];
  const unsigned char* umk = (const unsigned char*)d_in[3];
  float* out = (float*)d_out;
  float* pw  = (float*)d_ws;   // 64 block partials

  crf_fwd<<<dim3(64), dim3(512), 0, stream>>>(emit, trn, msk, umk, pw);
  reduce_partials<<<dim3(1), dim3(64), 0, stream>>>(pw, out);
}